// Round 8
// baseline (122.474 us; speedup 1.0000x reference)
//
#include <hip/hip_runtime.h>
#include <math.h>

#define KN 1024
#define KB 128
#define KDT 0.1f
#define KSTEPS 10
#define KMAGIC 0xB0000000u     // > 0xAAAAAAAA poison: stale poison never passes >=
#define PI_F 3.14159265358979f
#define TWO_PI_F 6.28318530717959f

typedef __attribute__((ext_vector_type(8))) short short8;
typedef __attribute__((ext_vector_type(4))) float floatx4;
typedef unsigned long long u64;

__device__ __forceinline__ unsigned short f2bf(float f) {
    unsigned u = __float_as_uint(f);
    u += 0x7FFF + ((u >> 16) & 1);          // round-to-nearest-even
    return (unsigned short)(u >> 16);
}

// X element = 8B: lo dword = (bf16 sin | bf16 cos<<16), hi dword = epoch tag.
// Epoch of X(t): e(t) = t+1 for t<=8, 11 for t=9. Harness poison 0xAAAAAAAA
// never equals a tag; with 3 rotating buffers, stale content in buffer s%3 is
// X(s-3) whose tag e(s-3) != e(s). Tag+payload travel in ONE 8B atomic store,
// so a matching tag certifies the payload with zero ordering assumptions.
//
// Layout (R3-verified; per group g: 16384 u64), element (b15=b&15, k):
//   u64 idx = g*16384 + (k>>5)*512 + (k&7)*64 + ((k>>3)&3)*16 + b15
// Chunk c=(k>>5) is written entirely by producer block (g, ib=c).
// Consumer wave kq reads chunks kq*4..kq*4+3: u64 at
//   [g*16384 + (kq*4+it)*512 + h*64 + lane], lane=quad*16+b15 — 32 dense
// 512B wave-loads; fragment slot a_[h] <-> k = quad*8+h (verified R3 pass).
__device__ __forceinline__ unsigned xoff64(int grp, int b15, int k) {
    return (unsigned)(grp * 16384 + (k >> 5) * 512 + (k & 7) * 64 +
                      ((k >> 3) & 3) * 16 + b15);
}

// Single kernel, plain launch (graph-capturable).
// Grid 256 = 8 batch-groups(16 b) x 32 i-blocks(32 cols); block 512 thr = 8 waves.
// R8 = R7's proven skeleton (block flags after drain barrier; narrow 4-flag
// 128B-line poll; two barriers/step; single ldsY) + ONE delta: the consumer
// merges detect+load. At step entry it optimistically issues its 32 tagged
// u64 A-loads and validates tags in registers; steady state all match ->
// the flag-poll RT is eliminated (one fabric RT instead of two). On any
// mismatch: proven flag poll, then ONE reload burst (no data-retry loops ->
// no R3/R9 flood). Flags/barriers unchanged -> reuse-safety chain unchanged:
// overwrite of X(s-2) at end of step s is ordered after this block validated
// all 32 chunks of X(s) => every block passed barrier(s-1) => all
// step-(s-1)/(s-2) A-loads retired.
// Dead ends (measured): retry-until-valid data polling floods fabric (R9/R3);
// per-wave flags wait on max-over-32 store visibilities, +13us (R6);
// sc0 globals are not cross-CU coherence primitives (R5, 5.8s stalls).
__global__ __launch_bounds__(512)
void k_main(const float* __restrict__ theta0,
            const float* __restrict__ Kmat,
            const float* __restrict__ omega,
            const float* __restrict__ kg,
            float* __restrict__ out_theta,
            float* __restrict__ out_coh,
            unsigned* __restrict__ flags,        // 256 contiguous; group g = [g*32, g*32+32)
            float* __restrict__ acc,             // coherence accum: 2*128 slots, 64B stride
            u64* __restrict__ xbuf)              // 3 rotating buffers of KB*KN u64
{
    const int grp = blockIdx.x >> 5;
    const int b0  = grp * 16;
    const int i0  = (blockIdx.x & 31) * 32;

    const int tid  = threadIdx.x;
    const int lane = tid & 63;
    const int kq   = tid >> 6;              // wave = k-eighth
    const int r16  = lane & 15;
    const int quad = lane >> 4;

    __shared__ float ldsY[8][2][16][34];    // [kq][S/C][m][il+pad] 34.8 KB

    // group leader zeroes its coherence accumulators (before publishing flag 0,
    // so every block's end-of-kernel atomicAdd is ordered after the zeroing)
    if ((blockIdx.x & 31) == 0 && tid < 16) {
        __hip_atomic_store(&acc[(b0 + tid) * 16], 0.f, __ATOMIC_RELAXED,
                           __HIP_MEMORY_SCOPE_AGENT);
        __hip_atomic_store(&acc[2048 + (b0 + tid) * 16], 0.f, __ATOMIC_RELAXED,
                           __HIP_MEMORY_SCOPE_AGENT);
    }

    // ---- B fragments (both wi) fp32->bf16 into registers; K symmetric.
    short8 bfrag[2][4];
    #pragma unroll
    for (int wi = 0; wi < 2; ++wi) {
        const float* kp = Kmat + (size_t)(i0 + wi * 16 + r16) * KN + kq * 128 + quad * 8;
        #pragma unroll
        for (int it = 0; it < 4; ++it) {
            const float4 v0 = *reinterpret_cast<const float4*>(kp + it * 32);
            const float4 v1 = *reinterpret_cast<const float4*>(kp + it * 32 + 4);
            short8 b_;
            b_[0] = (short)f2bf(v0.x); b_[1] = (short)f2bf(v0.y);
            b_[2] = (short)f2bf(v0.z); b_[3] = (short)f2bf(v0.w);
            b_[4] = (short)f2bf(v1.x); b_[5] = (short)f2bf(v1.y);
            b_[6] = (short)f2bf(v1.z); b_[7] = (short)f2bf(v1.w);
            bfrag[wi][it] = b_;
        }
    }

    // ---- per-thread theta state (block-private tile, 1 elem/thread).
    const int eb = b0 + (tid >> 5);          // batch
    const int ei = i0 + (tid & 31);          // column
    float th_reg = theta0[(size_t)eb * KN + ei];
    const float omg = omega[ei];
    float sn, cs;
    __sincosf(th_reg, &sn, &cs);
    u64* xb[3] = {xbuf, xbuf + (size_t)KB * KN, xbuf + 2 * (size_t)KB * KN};
    const unsigned xoff = xoff64(grp, eb & 15, ei);
    __hip_atomic_store(&xb[0][xoff],
                       (u64)((unsigned)f2bf(sn) | ((unsigned)f2bf(cs) << 16)) |
                           (1ull << 32),
                       __ATOMIC_RELAXED, __HIP_MEMORY_SCOPE_AGENT);
    const float scale = kg[0] * (1.0f / (float)KN);

    __syncthreads();                         // drain X(0) stores (vmcnt(0))
    if (tid == 0)
        __hip_atomic_store(&flags[blockIdx.x], KMAGIC + 0u,
                           __ATOMIC_RELAXED, __HIP_MEMORY_SCOPE_AGENT);

    // Fallback dataflow wait: lanes 0..3 poll this wave's 4 producer flags
    // (contiguous -> single 128 B line). Monotone >= compare.
    auto wait_chunks = [&](unsigned tgt) {
        unsigned polls = 0;
        for (;;) {
            unsigned v = tgt;
            if (lane < 4)
                v = __hip_atomic_load(&flags[grp * 32 + kq * 4 + lane],
                                      __ATOMIC_RELAXED, __HIP_MEMORY_SCOPE_AGENT);
            if (__ballot(v >= tgt) == ~0ull) break;
            if (++polls > 4000000u) break;   // failsafe: fail visibly, not hang
            __builtin_amdgcn_s_sleep(1);
        }
        asm volatile("" ::: "memory");       // reloads must not hoist above poll
    };

    float s2 = sn, c2 = cs;
    for (int s = 0; s < KSTEPS; ++s) {
        const unsigned es = (s == 9) ? 11u : (unsigned)(s + 1);   // expected tag

        // ---- A stage: optimistic 32 dense u64 loads; tags validate freshness.
        const u64* xg = xb[s % 3] + grp * 16384 + kq * 2048 + lane;
        u64 aw[4][8];
        #pragma unroll
        for (int it = 0; it < 4; ++it)
            #pragma unroll
            for (int h = 0; h < 8; ++h)
                aw[it][h] = __hip_atomic_load(xg + it * 512 + h * 64,
                                              __ATOMIC_RELAXED,
                                              __HIP_MEMORY_SCOPE_AGENT);
        {
            int ok = 1;
            #pragma unroll
            for (int it = 0; it < 4; ++it)
                #pragma unroll
                for (int h = 0; h < 8; ++h)
                    ok &= ((unsigned)(aw[it][h] >> 32) == es);
            if (__ballot(ok != 0) != ~0ull) {
                // miss: proven flag-gated path, then ONE reload burst
                wait_chunks(KMAGIC + (unsigned)s);
                #pragma unroll
                for (int it = 0; it < 4; ++it)
                    #pragma unroll
                    for (int h = 0; h < 8; ++h)
                        aw[it][h] = __hip_atomic_load(xg + it * 512 + h * 64,
                                                      __ATOMIC_RELAXED,
                                                      __HIP_MEMORY_SCOPE_AGENT);
            }
        }

        // ---- extract + MFMA (both wi subtiles)
        floatx4 accS[2] = {{0.f,0.f,0.f,0.f},{0.f,0.f,0.f,0.f}};
        floatx4 accC[2] = {{0.f,0.f,0.f,0.f},{0.f,0.f,0.f,0.f}};
        #pragma unroll
        for (int it = 0; it < 4; ++it) {
            short8 a_s, a_c;
            #pragma unroll
            for (int h = 0; h < 8; ++h) {
                const unsigned lo = (unsigned)aw[it][h];
                a_s[h] = (short)(lo & 0xffffu);
                a_c[h] = (short)(lo >> 16);
            }
            #pragma unroll
            for (int wi = 0; wi < 2; ++wi) {
                accS[wi] = __builtin_amdgcn_mfma_f32_16x16x32_bf16(a_s, bfrag[wi][it], accS[wi], 0, 0, 0);
                accC[wi] = __builtin_amdgcn_mfma_f32_16x16x32_bf16(a_c, bfrag[wi][it], accC[wi], 0, 0, 0);
            }
        }
        #pragma unroll
        for (int wi = 0; wi < 2; ++wi)
            #pragma unroll
            for (int r = 0; r < 4; ++r) {
                ldsY[kq][0][quad * 4 + r][wi * 16 + r16] = accS[wi][r];  // D[m=quad*4+r][n=r16]
                ldsY[kq][1][quad * 4 + r][wi * 16 + r16] = accC[wi][r];
            }
        __syncthreads();

        // ---- Euler update + branch-wrap (1 elem/thread)
        {
            const int bl = tid >> 5, ilo = tid & 31;
            float Ys = 0.f, Yc = 0.f;
            #pragma unroll
            for (int q = 0; q < 8; ++q) {
                Ys += ldsY[q][0][bl][ilo];
                Yc += ldsY[q][1][bl][ilo];
            }
            const float coupling = cs * Ys - sn * Yc;   // sum_j K[i,j] sin(th_j - th_i)
            float tn = th_reg + KDT * (omg + scale * coupling);
            __sincosf(tn, &s2, &c2);                    // also next step's (sn,cs)
            if (tn > PI_F)       tn -= TWO_PI_F;        // == atan2f(s2,c2) to ~1e-7
            else if (tn < -PI_F) tn += TWO_PI_F;
            th_reg = tn;
            sn = s2; cs = c2;
        }
        if (s < KSTEPS - 1) {
            const unsigned e1 = (s == 8) ? 11u : (unsigned)(s + 2);
            __hip_atomic_store(&xb[(s + 1) % 3][xoff],
                               (u64)((unsigned)f2bf(s2) | ((unsigned)f2bf(c2) << 16)) |
                                   ((u64)e1 << 32),
                               __ATOMIC_RELAXED, __HIP_MEMORY_SCOPE_AGENT);
            __syncthreads();                 // drain X(s+1) stores; guards ldsY reuse
            if (tid == 0)
                __hip_atomic_store(&flags[blockIdx.x], KMAGIC + (unsigned)(s + 1),
                                   __ATOMIC_RELAXED, __HIP_MEMORY_SCOPE_AGENT);
        } else {
            out_theta[(size_t)eb * KN + ei] = th_reg;
        }
    }

    // ---- coherence: block-local reduce over its 32 cols, then padded atomics
    __syncthreads();                         // epilogue ldsY reads done
    float* red = &ldsY[0][0][0][0];
    red[tid]       = s2;                     // == sin(theta_final) to ~1e-7
    red[512 + tid] = c2;
    __syncthreads();
    if (tid < 16) {
        float ss = 0.f, cc = 0.f;
        #pragma unroll
        for (int il2 = 0; il2 < 32; ++il2) {
            ss += red[tid * 32 + il2];
            cc += red[512 + tid * 32 + il2];
        }
        atomicAdd(&acc[(b0 + tid) * 16], ss);           // 64B-stride slots
        atomicAdd(&acc[2048 + (b0 + tid) * 16], cc);
    }
    __syncthreads();                         // drain atomics (vmcnt(0))
    if (tid == 0)
        __hip_atomic_store(&flags[blockIdx.x], KMAGIC + (unsigned)KSTEPS,
                           __ATOMIC_RELAXED, __HIP_MEMORY_SCOPE_AGENT);

    // group leader: wait all 32 blocks' adds, then write out_coh
    if ((blockIdx.x & 31) == 0) {
        if (tid < 64) {
            const unsigned tgt = KMAGIC + (unsigned)KSTEPS;
            unsigned polls = 0;
            for (;;) {
                unsigned v = tgt;
                if (lane < 32)
                    v = __hip_atomic_load(&flags[grp * 32 + lane],
                                          __ATOMIC_RELAXED, __HIP_MEMORY_SCOPE_AGENT);
                if (__ballot(v >= tgt) == ~0ull) break;
                if (++polls > 4000000u) break;
                __builtin_amdgcn_s_sleep(2);
            }
        }
        asm volatile("" ::: "memory");       // acc reads must not hoist above poll
        __syncthreads();
        if (tid < 16) {
            float sv = __hip_atomic_load(&acc[(b0 + tid) * 16],
                                         __ATOMIC_RELAXED, __HIP_MEMORY_SCOPE_AGENT);
            float cv = __hip_atomic_load(&acc[2048 + (b0 + tid) * 16],
                                         __ATOMIC_RELAXED, __HIP_MEMORY_SCOPE_AGENT);
            float sm = sv * (1.0f / (float)KN);
            float cm = cv * (1.0f / (float)KN);
            out_coh[b0 + tid] = sqrtf(cm * cm + sm * sm);
        }
    }
}

extern "C" void kernel_launch(void* const* d_in, const int* in_sizes, int n_in,
                              void* d_out, int out_size, void* d_ws, size_t ws_size,
                              hipStream_t stream)
{
    (void)in_sizes; (void)n_in; (void)out_size; (void)ws_size;

    const float* theta0 = (const float*)d_in[0];
    const float* Kmat   = (const float*)d_in[1];
    const float* omega  = (const float*)d_in[2];
    const float* kg     = (const float*)d_in[3];

    float* out_theta = (float*)d_out;                    // 128*1024 f32
    float* out_coh   = out_theta + (size_t)KB * KN;      // +128 f32

    // ws: flags[256] u32 @0 (1 KB) | acc 16 KB @4096 | xbuf u64 @32768:
    //     3 rotating buffers of KB*KN u64 (1 MB each, L3-resident).
    // Harness re-poisons ws with 0xAAAAAAAA each call: poison < KMAGIC and
    // poison != any epoch tag {1..9,11}, so all protocol state self-resets.
    unsigned* flags = (unsigned*)d_ws;
    float* acc      = (float*)((char*)d_ws + 4096);
    u64* xbuf       = (u64*)((char*)d_ws + 32768);

    k_main<<<256, 512, 0, stream>>>(theta0, Kmat, omega, kg,
                                    out_theta, out_coh, flags, acc, xbuf);
}